// Round 1
// baseline (126.675 us; speedup 1.0000x reference)
//
#include <hip/hip_runtime.h>
#include <float.h>

#define NPTS 8192
#define BLK  256
#define CHUNKS (NPTS / BLK)   // 32 query chunks per (batch, direction)

// Main kernel: one block per (batch b, direction dir, query-chunk).
// Stages all 8192 reference points into LDS as float4(x, y, z, |s|^2),
// then each thread scans all refs for its single query point.
// d = |q|^2 + (|s|^2 - 2 q.s); |q|^2 is added after the min.
__global__ __launch_bounds__(BLK) void chamfer_min_kernel(
    const float* __restrict__ tpl, const float* __restrict__ src,
    float* __restrict__ partial) {
  __shared__ float4 s4[NPTS];     // 128 KB
  __shared__ float wsum[BLK / 64];

  const int b   = blockIdx.z;
  const int dir = blockIdx.y;
  const float* qb = (dir == 0 ? tpl : src) + (size_t)b * NPTS * 3;
  const float* rb = (dir == 0 ? src : tpl) + (size_t)b * NPTS * 3;
  const int t = threadIdx.x;

  // Stage reference points (coalesced-ish: lane-adjacent points, stride 12B).
  #pragma unroll
  for (int k = 0; k < NPTS / BLK; ++k) {
    int p = t + BLK * k;
    float x = rb[3 * p + 0];
    float y = rb[3 * p + 1];
    float z = rb[3 * p + 2];
    s4[p] = make_float4(x, y, z, fmaf(x, x, fmaf(y, y, z * z)));
  }

  // Load this thread's query point.
  int q = blockIdx.x * BLK + t;
  float qx = qb[3 * q + 0];
  float qy = qb[3 * q + 1];
  float qz = qb[3 * q + 2];
  float q2 = fmaf(qx, qx, fmaf(qy, qy, qz * qz));

  __syncthreads();

  // 4 independent min accumulators to break the fmin dependency chain.
  float b0 = FLT_MAX, b1 = FLT_MAX, b2 = FLT_MAX, b3 = FLT_MAX;
  #pragma unroll 2
  for (int m = 0; m < NPTS; m += 4) {
    float4 p0 = s4[m + 0];   // wave-uniform address -> LDS broadcast
    float4 p1 = s4[m + 1];
    float4 p2 = s4[m + 2];
    float4 p3 = s4[m + 3];
    float d0 = fmaf(qx, p0.x, fmaf(qy, p0.y, qz * p0.z));
    float d1 = fmaf(qx, p1.x, fmaf(qy, p1.y, qz * p1.z));
    float d2 = fmaf(qx, p2.x, fmaf(qy, p2.y, qz * p2.z));
    float d3 = fmaf(qx, p3.x, fmaf(qy, p3.y, qz * p3.z));
    b0 = fminf(b0, fmaf(d0, -2.0f, p0.w));
    b1 = fminf(b1, fmaf(d1, -2.0f, p1.w));
    b2 = fminf(b2, fmaf(d2, -2.0f, p2.w));
    b3 = fminf(b3, fmaf(d3, -2.0f, p3.w));
  }
  float best = fminf(fminf(b0, b1), fminf(b2, b3)) + q2;

  // Block-level sum of per-query min distances.
  float v = best;
  #pragma unroll
  for (int off = 32; off > 0; off >>= 1) v += __shfl_down(v, off, 64);
  if ((t & 63) == 0) wsum[t >> 6] = v;
  __syncthreads();
  if (t == 0) {
    float s = wsum[0] + wsum[1] + wsum[2] + wsum[3];
    partial[((b * 2 + dir) * CHUNKS) + blockIdx.x] = s;
  }
}

// Deterministic finalize: fixed-order reduction of the 256 block partials.
// out = (sum of all 65536 per-query mins) / (8192 * 4)
__global__ __launch_bounds__(BLK) void chamfer_reduce_kernel(
    const float* __restrict__ partial, float* __restrict__ out) {
  __shared__ float wsum[BLK / 64];
  int t = threadIdx.x;
  float v = partial[t];
  #pragma unroll
  for (int off = 32; off > 0; off >>= 1) v += __shfl_down(v, off, 64);
  if ((t & 63) == 0) wsum[t >> 6] = v;
  __syncthreads();
  if (t == 0) {
    out[0] = (wsum[0] + wsum[1] + wsum[2] + wsum[3]) * (1.0f / 32768.0f);
  }
}

extern "C" void kernel_launch(void* const* d_in, const int* in_sizes, int n_in,
                              void* d_out, int out_size, void* d_ws, size_t ws_size,
                              hipStream_t stream) {
  const float* tpl = (const float*)d_in[0];   // template (4, 8192, 3) f32
  const float* src = (const float*)d_in[1];   // source   (4, 8192, 3) f32
  float* out = (float*)d_out;                 // scalar f32
  float* partial = (float*)d_ws;              // 256 floats of scratch

  dim3 grid(CHUNKS, 2, 4);                    // 32 chunks x 2 directions x 4 batches
  chamfer_min_kernel<<<grid, BLK, 0, stream>>>(tpl, src, partial);
  chamfer_reduce_kernel<<<1, BLK, 0, stream>>>(partial, out);
}

// Round 2
// 114.609 us; speedup vs baseline: 1.1053x; 1.1053x over previous
//
#include <hip/hip_runtime.h>
#include <float.h>

#define NPTS   8192
#define BLK    256
#define TILE   2048                 // 32 KB LDS tile -> multiple blocks/CU
#define NTILES (NPTS / TILE)
#define CHUNKS (NPTS / BLK)         // 32 query chunks per (batch, direction)

// One block per (batch b, direction dir, 256-query chunk).
// Refs staged in 4 tiles of 2048 as float4(-2x, -2y, -2z, |s|^2) so the
// inner pair is 3 fma + 1 min:  d - |q|^2 = fma(qx,-2x, fma(qy,-2y, fma(qz,-2z, s2)))
__global__ __launch_bounds__(BLK) void chamfer_min_kernel(
    const float* __restrict__ tpl, const float* __restrict__ src,
    float* __restrict__ partial) {
  __shared__ float4 s4[TILE];       // 32 KB
  __shared__ float wsum[BLK / 64];

  const int b   = blockIdx.z;
  const int dir = blockIdx.y;
  const float* qb = (dir == 0 ? tpl : src) + (size_t)b * NPTS * 3;
  const float* rb = (dir == 0 ? src : tpl) + (size_t)b * NPTS * 3;
  const int t = threadIdx.x;

  // This thread's query point (kept in registers for the whole kernel).
  const int q = blockIdx.x * BLK + t;
  const float qx = qb[3 * q + 0];
  const float qy = qb[3 * q + 1];
  const float qz = qb[3 * q + 2];
  const float q2 = fmaf(qx, qx, fmaf(qy, qy, qz * qz));

  // 4 independent min accumulators break the fmin dependency chain.
  float b0 = FLT_MAX, b1 = FLT_MAX, b2 = FLT_MAX, b3 = FLT_MAX;

  for (int tile = 0; tile < NTILES; ++tile) {
    // Stage 2048 ref points, pre-scaled.
    const float* rt = rb + 3 * TILE * tile;
    #pragma unroll
    for (int k = 0; k < TILE / BLK; ++k) {
      int p = t + BLK * k;
      float x = rt[3 * p + 0];
      float y = rt[3 * p + 1];
      float z = rt[3 * p + 2];
      s4[p] = make_float4(-2.0f * x, -2.0f * y, -2.0f * z,
                          fmaf(x, x, fmaf(y, y, z * z)));
    }
    __syncthreads();

    #pragma unroll 2
    for (int m = 0; m < TILE; m += 4) {
      float4 p0 = s4[m + 0];        // wave-uniform address -> LDS broadcast
      float4 p1 = s4[m + 1];
      float4 p2 = s4[m + 2];
      float4 p3 = s4[m + 3];
      b0 = fminf(b0, fmaf(qx, p0.x, fmaf(qy, p0.y, fmaf(qz, p0.z, p0.w))));
      b1 = fminf(b1, fmaf(qx, p1.x, fmaf(qy, p1.y, fmaf(qz, p1.z, p1.w))));
      b2 = fminf(b2, fmaf(qx, p2.x, fmaf(qy, p2.y, fmaf(qz, p2.z, p2.w))));
      b3 = fminf(b3, fmaf(qx, p3.x, fmaf(qy, p3.y, fmaf(qz, p3.z, p3.w))));
    }
    __syncthreads();
  }
  float best = fminf(fminf(b0, b1), fminf(b2, b3)) + q2;

  // Block-level sum of per-query min distances.
  float v = best;
  #pragma unroll
  for (int off = 32; off > 0; off >>= 1) v += __shfl_down(v, off, 64);
  if ((t & 63) == 0) wsum[t >> 6] = v;
  __syncthreads();
  if (t == 0) {
    float s = wsum[0] + wsum[1] + wsum[2] + wsum[3];
    partial[((b * 2 + dir) * CHUNKS) + blockIdx.x] = s;
  }
}

// Deterministic finalize: fixed-order reduction of the 256 block partials.
__global__ __launch_bounds__(BLK) void chamfer_reduce_kernel(
    const float* __restrict__ partial, float* __restrict__ out) {
  __shared__ float wsum[BLK / 64];
  int t = threadIdx.x;
  float v = partial[t];
  #pragma unroll
  for (int off = 32; off > 0; off >>= 1) v += __shfl_down(v, off, 64);
  if ((t & 63) == 0) wsum[t >> 6] = v;
  __syncthreads();
  if (t == 0) {
    out[0] = (wsum[0] + wsum[1] + wsum[2] + wsum[3]) * (1.0f / 32768.0f);
  }
}

extern "C" void kernel_launch(void* const* d_in, const int* in_sizes, int n_in,
                              void* d_out, int out_size, void* d_ws, size_t ws_size,
                              hipStream_t stream) {
  const float* tpl = (const float*)d_in[0];   // template (4, 8192, 3) f32
  const float* src = (const float*)d_in[1];   // source   (4, 8192, 3) f32
  float* out = (float*)d_out;                 // scalar f32
  float* partial = (float*)d_ws;              // 256 floats of scratch

  dim3 grid(CHUNKS, 2, 4);                    // 32 chunks x 2 directions x 4 batches
  chamfer_min_kernel<<<grid, BLK, 0, stream>>>(tpl, src, partial);
  chamfer_reduce_kernel<<<1, BLK, 0, stream>>>(partial, out);
}

// Round 3
// 60.721 us; speedup vs baseline: 2.0862x; 1.8875x over previous
//
#include <hip/hip_runtime.h>
#include <float.h>

#define NPTS   8192
#define NB     4
#define BLK    256
#define Q      8                        // queries per thread (register-resident)
#define RSLICE 256                      // ref points per block slice (4 KB LDS)
#define NSLICE (NPTS / RSLICE)          // 32 ref slices
#define QPB    (BLK * Q)                // 2048 queries per block
#define NCHUNK (NPTS / QPB)             // 4 query chunks
#define NBDIR  (NB * 2)                 // 8 (batch, direction) pairs

// ---------------- main path: 1024 blocks, Q=8 queries/thread ----------------
// Each block: one ref slice (256 pts staged in LDS as (-2x,-2y,-2z,|s|^2)),
// 2048 queries. acc[i] = min over slice of (|s|^2 - 2 q.s); |q|^2 added later.
__global__ __launch_bounds__(BLK) void chamfer_slice_kernel(
    const float* __restrict__ tpl, const float* __restrict__ src,
    float* __restrict__ cand) {
  __shared__ float4 s4[RSLICE];         // 4 KB
  const int s  = blockIdx.x;            // ref slice
  const int c  = blockIdx.y;            // query chunk
  const int bd = blockIdx.z;            // b*2 + dir
  const int b = bd >> 1, dir = bd & 1;
  const float* qb = (dir == 0 ? tpl : src) + (size_t)b * NPTS * 3;
  const float* rb = (dir == 0 ? src : tpl) + (size_t)b * NPTS * 3;
  const int t = threadIdx.x;

  // Stage this block's 256-point ref slice, pre-scaled.
  {
    int p = s * RSLICE + t;
    float x = rb[3 * p + 0];
    float y = rb[3 * p + 1];
    float z = rb[3 * p + 2];
    s4[t] = make_float4(-2.0f * x, -2.0f * y, -2.0f * z,
                        fmaf(x, x, fmaf(y, y, z * z)));
  }

  // Load 8 queries per thread into registers (stride-BLK for coalescing).
  float qx[Q], qy[Q], qz[Q];
  #pragma unroll
  for (int i = 0; i < Q; ++i) {
    int q = c * QPB + t + BLK * i;
    qx[i] = qb[3 * q + 0];
    qy[i] = qb[3 * q + 1];
    qz[i] = qb[3 * q + 2];
  }

  float acc[Q];
  #pragma unroll
  for (int i = 0; i < Q; ++i) acc[i] = FLT_MAX;

  __syncthreads();

  // One broadcast ds_read_b128 feeds 32 VALU ops (8 queries x 4).
  #pragma unroll 2
  for (int m = 0; m < RSLICE; ++m) {
    float4 p = s4[m];
    #pragma unroll
    for (int i = 0; i < Q; ++i)
      acc[i] = fminf(acc[i],
                     fmaf(qx[i], p.x, fmaf(qy[i], p.y, fmaf(qz[i], p.z, p.w))));
  }

  // Coalesced candidate write: cand[bd][c][s][2048 queries].
  float* dst = cand + (((size_t)(bd * NCHUNK + c) * NSLICE + s) * QPB);
  #pragma unroll
  for (int i = 0; i < Q; ++i) dst[t + BLK * i] = acc[i];
}

// Combine: per (bd, chunk), min over 32 slices per query, add |q|^2, sum.
__global__ __launch_bounds__(BLK) void chamfer_combine_kernel(
    const float* __restrict__ tpl, const float* __restrict__ src,
    const float* __restrict__ cand, float* __restrict__ partial) {
  __shared__ float wsum[BLK / 64];
  const int c  = blockIdx.x;
  const int bd = blockIdx.y;
  const int b = bd >> 1, dir = bd & 1;
  const float* qb = (dir == 0 ? tpl : src) + (size_t)b * NPTS * 3;
  const int t = threadIdx.x;
  const float* base = cand + ((size_t)(bd * NCHUNK + c) * NSLICE) * QPB;

  float sum = 0.0f;
  #pragma unroll
  for (int i = 0; i < Q; ++i) {
    int ql = t + BLK * i;
    float v = FLT_MAX;
    for (int si = 0; si < NSLICE; ++si)
      v = fminf(v, base[(size_t)si * QPB + ql]);
    int q = c * QPB + ql;
    float x = qb[3 * q + 0], y = qb[3 * q + 1], z = qb[3 * q + 2];
    sum += v + fmaf(x, x, fmaf(y, y, z * z));
  }
  float v = sum;
  #pragma unroll
  for (int off = 32; off > 0; off >>= 1) v += __shfl_down(v, off, 64);
  if ((t & 63) == 0) wsum[t >> 6] = v;
  __syncthreads();
  if (t == 0)
    partial[bd * NCHUNK + c] = wsum[0] + wsum[1] + wsum[2] + wsum[3];
}

// Final: fixed-order sum of 32 partials, mean over 2*N*B = 32768 per-query mins.
__global__ void chamfer_final_kernel(const float* __restrict__ partial,
                                     float* __restrict__ out) {
  int t = threadIdx.x;                  // 64 threads
  float v = (t < NBDIR * NCHUNK) ? partial[t] : 0.0f;
  #pragma unroll
  for (int off = 32; off > 0; off >>= 1) v += __shfl_down(v, off, 64);
  if (t == 0) out[0] = v * (1.0f / 32768.0f);
}

// ---------------- fallback path (R2 kernel) if ws is too small --------------
#define TILE   2048
#define NTILES (NPTS / TILE)
#define CHUNKS (NPTS / BLK)

__global__ __launch_bounds__(BLK) void chamfer_min_kernel(
    const float* __restrict__ tpl, const float* __restrict__ src,
    float* __restrict__ partial) {
  __shared__ float4 s4[TILE];
  __shared__ float wsum[BLK / 64];
  const int b = blockIdx.z, dir = blockIdx.y;
  const float* qb = (dir == 0 ? tpl : src) + (size_t)b * NPTS * 3;
  const float* rb = (dir == 0 ? src : tpl) + (size_t)b * NPTS * 3;
  const int t = threadIdx.x;
  const int q = blockIdx.x * BLK + t;
  const float qx = qb[3 * q + 0], qy = qb[3 * q + 1], qz = qb[3 * q + 2];
  const float q2 = fmaf(qx, qx, fmaf(qy, qy, qz * qz));
  float b0 = FLT_MAX, b1 = FLT_MAX, b2 = FLT_MAX, b3 = FLT_MAX;
  for (int tile = 0; tile < NTILES; ++tile) {
    const float* rt = rb + 3 * TILE * tile;
    #pragma unroll
    for (int k = 0; k < TILE / BLK; ++k) {
      int p = t + BLK * k;
      float x = rt[3 * p + 0], y = rt[3 * p + 1], z = rt[3 * p + 2];
      s4[p] = make_float4(-2.0f * x, -2.0f * y, -2.0f * z,
                          fmaf(x, x, fmaf(y, y, z * z)));
    }
    __syncthreads();
    #pragma unroll 2
    for (int m = 0; m < TILE; m += 4) {
      float4 p0 = s4[m + 0], p1 = s4[m + 1], p2 = s4[m + 2], p3 = s4[m + 3];
      b0 = fminf(b0, fmaf(qx, p0.x, fmaf(qy, p0.y, fmaf(qz, p0.z, p0.w))));
      b1 = fminf(b1, fmaf(qx, p1.x, fmaf(qy, p1.y, fmaf(qz, p1.z, p1.w))));
      b2 = fminf(b2, fmaf(qx, p2.x, fmaf(qy, p2.y, fmaf(qz, p2.z, p2.w))));
      b3 = fminf(b3, fmaf(qx, p3.x, fmaf(qy, p3.y, fmaf(qz, p3.z, p3.w))));
    }
    __syncthreads();
  }
  float best = fminf(fminf(b0, b1), fminf(b2, b3)) + q2;
  float v = best;
  #pragma unroll
  for (int off = 32; off > 0; off >>= 1) v += __shfl_down(v, off, 64);
  if ((t & 63) == 0) wsum[t >> 6] = v;
  __syncthreads();
  if (t == 0)
    partial[((b * 2 + dir) * CHUNKS) + blockIdx.x] =
        wsum[0] + wsum[1] + wsum[2] + wsum[3];
}

__global__ __launch_bounds__(BLK) void chamfer_reduce_kernel(
    const float* __restrict__ partial, float* __restrict__ out) {
  __shared__ float wsum[BLK / 64];
  int t = threadIdx.x;
  float v = partial[t];
  #pragma unroll
  for (int off = 32; off > 0; off >>= 1) v += __shfl_down(v, off, 64);
  if ((t & 63) == 0) wsum[t >> 6] = v;
  __syncthreads();
  if (t == 0) out[0] = (wsum[0] + wsum[1] + wsum[2] + wsum[3]) * (1.0f / 32768.0f);
}

// ----------------------------------------------------------------------------
extern "C" void kernel_launch(void* const* d_in, const int* in_sizes, int n_in,
                              void* d_out, int out_size, void* d_ws, size_t ws_size,
                              hipStream_t stream) {
  const float* tpl = (const float*)d_in[0];   // template (4, 8192, 3) f32
  const float* src = (const float*)d_in[1];   // source   (4, 8192, 3) f32
  float* out = (float*)d_out;

  const size_t cand_elems = (size_t)NBDIR * NCHUNK * NSLICE * QPB;  // 2 M floats
  const size_t need = (cand_elems + NBDIR * NCHUNK) * sizeof(float); // ~8 MB

  if (ws_size >= need) {
    float* cand    = (float*)d_ws;
    float* partial = cand + cand_elems;
    dim3 grid(NSLICE, NCHUNK, NBDIR);       // 32 x 4 x 8 = 1024 blocks
    chamfer_slice_kernel<<<grid, BLK, 0, stream>>>(tpl, src, cand);
    dim3 cgrid(NCHUNK, NBDIR);              // 4 x 8 = 32 blocks
    chamfer_combine_kernel<<<cgrid, BLK, 0, stream>>>(tpl, src, cand, partial);
    chamfer_final_kernel<<<1, 64, 0, stream>>>(partial, out);
  } else {
    float* partial = (float*)d_ws;          // 256 floats
    dim3 grid(CHUNKS, 2, NB);
    chamfer_min_kernel<<<grid, BLK, 0, stream>>>(tpl, src, partial);
    chamfer_reduce_kernel<<<1, BLK, 0, stream>>>(partial, out);
  }
}

// Round 4
// 56.046 us; speedup vs baseline: 2.2602x; 1.0834x over previous
//
#include <hip/hip_runtime.h>
#include <float.h>

#define NPTS   8192
#define NB     4
#define BLK    256
#define Q      8                        // queries per thread (register-resident)
#define QPB    (BLK * Q)                // 2048 queries per block
#define NCHUNK (NPTS / QPB)             // 4 query chunks
#define NBDIR  (NB * 2)                 // 8 (batch, direction) pairs
#define QBLKS  (NPTS / BLK)             // 32 query blocks for combine

// ---------------- main path: split-refs, Q=8 queries/thread -----------------
// Each block: one ref slice staged in LDS as (-2x,-2y,-2z,|s|^2), 2048 queries.
// acc[i] = min over slice of (|s|^2 - 2 q.s); |q|^2 added in combine.
// Inner: 2 refs/iter -> v_min3_f32 fusion => 3.5 VALU ops per pair.
template <int NSLICE>
__global__ __launch_bounds__(BLK) void chamfer_slice_kernel(
    const float* __restrict__ tpl, const float* __restrict__ src,
    float* __restrict__ cand) {
  constexpr int RSLICE = NPTS / NSLICE;
  __shared__ float4 s4[RSLICE];
  const int s  = blockIdx.x;            // ref slice
  const int c  = blockIdx.y;            // query chunk
  const int bd = blockIdx.z;            // b*2 + dir
  const int b = bd >> 1, dir = bd & 1;
  const float* qb = (dir == 0 ? tpl : src) + (size_t)b * NPTS * 3;
  const float* rb = (dir == 0 ? src : tpl) + (size_t)b * NPTS * 3;
  const int t = threadIdx.x;

  // Stage this block's ref slice, pre-scaled.
  #pragma unroll
  for (int k = 0; k < (RSLICE + BLK - 1) / BLK; ++k) {
    int idx = t + BLK * k;
    if (idx < RSLICE) {
      int p = s * RSLICE + idx;
      float x = rb[3 * p + 0];
      float y = rb[3 * p + 1];
      float z = rb[3 * p + 2];
      s4[idx] = make_float4(-2.0f * x, -2.0f * y, -2.0f * z,
                            fmaf(x, x, fmaf(y, y, z * z)));
    }
  }

  // 8 queries per thread in registers (stride-BLK for coalescing).
  float qx[Q], qy[Q], qz[Q], acc[Q];
  #pragma unroll
  for (int i = 0; i < Q; ++i) {
    int q = c * QPB + t + BLK * i;
    qx[i] = qb[3 * q + 0];
    qy[i] = qb[3 * q + 1];
    qz[i] = qb[3 * q + 2];
    acc[i] = FLT_MAX;
  }
  __syncthreads();

  // One broadcast ds_read_b128 feeds 28 VALU ops; 2 refs/iter for min3.
  #pragma unroll 4
  for (int m = 0; m < RSLICE; m += 2) {
    float4 p0 = s4[m + 0];
    float4 p1 = s4[m + 1];
    #pragma unroll
    for (int i = 0; i < Q; ++i) {
      float d0 = fmaf(qx[i], p0.x, fmaf(qy[i], p0.y, fmaf(qz[i], p0.z, p0.w)));
      float d1 = fmaf(qx[i], p1.x, fmaf(qy[i], p1.y, fmaf(qz[i], p1.z, p1.w)));
      acc[i] = fminf(acc[i], fminf(d0, d1));   // -> v_min3_f32
    }
  }

  // Coalesced candidate write: cand[bd][c][s][QPB].
  float* dst = cand + (((size_t)(bd * NCHUNK + c) * NSLICE + s) * QPB);
  #pragma unroll
  for (int i = 0; i < Q; ++i) dst[t + BLK * i] = acc[i];
}

// Combine: one thread per query; min over NSLICE slices, add |q|^2, block-sum.
template <int NSLICE>
__global__ __launch_bounds__(BLK) void chamfer_combine_kernel(
    const float* __restrict__ tpl, const float* __restrict__ src,
    const float* __restrict__ cand, float* __restrict__ partial) {
  __shared__ float wsum[BLK / 64];
  const int qblk = blockIdx.x;          // 0..31
  const int bd   = blockIdx.y;
  const int b = bd >> 1, dir = bd & 1;
  const float* qb = (dir == 0 ? tpl : src) + (size_t)b * NPTS * 3;
  const int t = threadIdx.x;
  const int q  = qblk * BLK + t;
  const int c  = q / QPB;
  const int ql = q - c * QPB;
  const float* base = cand + ((size_t)(bd * NCHUNK + c) * NSLICE) * QPB + ql;

  float v0 = FLT_MAX, v1 = FLT_MAX, v2 = FLT_MAX, v3 = FLT_MAX;
  #pragma unroll
  for (int si = 0; si < NSLICE; si += 4) {
    v0 = fminf(v0, base[(size_t)(si + 0) * QPB]);
    v1 = fminf(v1, base[(size_t)(si + 1) * QPB]);
    v2 = fminf(v2, base[(size_t)(si + 2) * QPB]);
    v3 = fminf(v3, base[(size_t)(si + 3) * QPB]);
  }
  float x = qb[3 * q + 0], y = qb[3 * q + 1], z = qb[3 * q + 2];
  float v = fminf(fminf(v0, v1), fminf(v2, v3)) +
            fmaf(x, x, fmaf(y, y, z * z));

  #pragma unroll
  for (int off = 32; off > 0; off >>= 1) v += __shfl_down(v, off, 64);
  if ((t & 63) == 0) wsum[t >> 6] = v;
  __syncthreads();
  if (t == 0)
    partial[bd * QBLKS + qblk] = wsum[0] + wsum[1] + wsum[2] + wsum[3];
}

// Final: fixed-order sum of 256 partials; mean over 2*B*N = 32768 mins.
__global__ __launch_bounds__(BLK) void chamfer_final_kernel(
    const float* __restrict__ partial, float* __restrict__ out) {
  __shared__ float wsum[BLK / 64];
  int t = threadIdx.x;
  float v = partial[t];
  #pragma unroll
  for (int off = 32; off > 0; off >>= 1) v += __shfl_down(v, off, 64);
  if ((t & 63) == 0) wsum[t >> 6] = v;
  __syncthreads();
  if (t == 0)
    out[0] = (wsum[0] + wsum[1] + wsum[2] + wsum[3]) * (1.0f / 32768.0f);
}

// ---------------- fallback path (R2 kernel) if ws is too small --------------
#define TILE   2048
#define NTILES (NPTS / TILE)

__global__ __launch_bounds__(BLK) void chamfer_min_kernel(
    const float* __restrict__ tpl, const float* __restrict__ src,
    float* __restrict__ partial) {
  __shared__ float4 s4[TILE];
  __shared__ float wsum[BLK / 64];
  const int b = blockIdx.z, dir = blockIdx.y;
  const float* qb = (dir == 0 ? tpl : src) + (size_t)b * NPTS * 3;
  const float* rb = (dir == 0 ? src : tpl) + (size_t)b * NPTS * 3;
  const int t = threadIdx.x;
  const int q = blockIdx.x * BLK + t;
  const float qx = qb[3 * q + 0], qy = qb[3 * q + 1], qz = qb[3 * q + 2];
  const float q2 = fmaf(qx, qx, fmaf(qy, qy, qz * qz));
  float b0 = FLT_MAX, b1 = FLT_MAX;
  for (int tile = 0; tile < NTILES; ++tile) {
    const float* rt = rb + 3 * TILE * tile;
    #pragma unroll
    for (int k = 0; k < TILE / BLK; ++k) {
      int p = t + BLK * k;
      float x = rt[3 * p + 0], y = rt[3 * p + 1], z = rt[3 * p + 2];
      s4[p] = make_float4(-2.0f * x, -2.0f * y, -2.0f * z,
                          fmaf(x, x, fmaf(y, y, z * z)));
    }
    __syncthreads();
    #pragma unroll 2
    for (int m = 0; m < TILE; m += 2) {
      float4 p0 = s4[m + 0], p1 = s4[m + 1];
      float d0 = fmaf(qx, p0.x, fmaf(qy, p0.y, fmaf(qz, p0.z, p0.w)));
      float d1 = fmaf(qx, p1.x, fmaf(qy, p1.y, fmaf(qz, p1.z, p1.w)));
      b0 = fminf(b0, fminf(d0, d1));
      b1 = fminf(b1, d0);  // keep a second chain for ILP
    }
    __syncthreads();
  }
  float best = fminf(b0, b1) + q2;
  float v = best;
  #pragma unroll
  for (int off = 32; off > 0; off >>= 1) v += __shfl_down(v, off, 64);
  if ((t & 63) == 0) wsum[t >> 6] = v;
  __syncthreads();
  if (t == 0)
    partial[((b * 2 + dir) * QBLKS) + blockIdx.x] =
        wsum[0] + wsum[1] + wsum[2] + wsum[3];
}

// ----------------------------------------------------------------------------
extern "C" void kernel_launch(void* const* d_in, const int* in_sizes, int n_in,
                              void* d_out, int out_size, void* d_ws, size_t ws_size,
                              hipStream_t stream) {
  const float* tpl = (const float*)d_in[0];   // template (4, 8192, 3) f32
  const float* src = (const float*)d_in[1];   // source   (4, 8192, 3) f32
  float* out = (float*)d_out;

  const size_t cand64 = (size_t)NBDIR * 64 * NPTS;   // 4 M floats (16 MB)
  const size_t cand32 = (size_t)NBDIR * 32 * NPTS;   // 2 M floats (8 MB)
  const size_t need64 = (cand64 + NBDIR * QBLKS) * sizeof(float);
  const size_t need32 = (cand32 + NBDIR * QBLKS) * sizeof(float);

  if (ws_size >= need64) {
    float* cand    = (float*)d_ws;
    float* partial = cand + cand64;
    dim3 grid(64, NCHUNK, NBDIR);             // 2048 blocks, 8/CU
    chamfer_slice_kernel<64><<<grid, BLK, 0, stream>>>(tpl, src, cand);
    dim3 cgrid(QBLKS, NBDIR);                 // 256 blocks
    chamfer_combine_kernel<64><<<cgrid, BLK, 0, stream>>>(tpl, src, cand, partial);
    chamfer_final_kernel<<<1, BLK, 0, stream>>>(partial, out);
  } else if (ws_size >= need32) {
    float* cand    = (float*)d_ws;
    float* partial = cand + cand32;
    dim3 grid(32, NCHUNK, NBDIR);             // 1024 blocks
    chamfer_slice_kernel<32><<<grid, BLK, 0, stream>>>(tpl, src, cand);
    dim3 cgrid(QBLKS, NBDIR);
    chamfer_combine_kernel<32><<<cgrid, BLK, 0, stream>>>(tpl, src, cand, partial);
    chamfer_final_kernel<<<1, BLK, 0, stream>>>(partial, out);
  } else {
    float* partial = (float*)d_ws;            // 256 floats
    dim3 grid(QBLKS, 2, NB);
    chamfer_min_kernel<<<grid, BLK, 0, stream>>>(tpl, src, partial);
    chamfer_final_kernel<<<1, BLK, 0, stream>>>(partial, out);
  }
}